// Round 6
// baseline (319.533 us; speedup 1.0000x reference)
//
#include <hip/hip_runtime.h>
#include <hip/hip_cooperative_groups.h>
#include <hip/hip_bf16.h>
#include <math.h>

// MultiHeadAttentionQuantum, B=2048 S=1 E=1024 H=128 DK=NW=8
// All inputs/outputs float32.
//
// Algebra: S==1 -> attention out == v = x @ Wv^T (wq,wk dead).
// RX compose additively; CNOTs are XOR basis permutations ->
//   t_j = cos(v_j + rx_j);  qout[0]=t1*...*t7;  qout[w>=1]=t0*...*tw
// out = qout @ Wc^T + bc
//
// R5 post-mortem: R4 and R5 GEMM structures identical in total time; kernels
// individually <41us so invisible in top-5 (harness 268MB poison fills at
// ~44us dominate). R6: ONE cooperative kernel (512 blk x 256 thr, 2 blk/CU)
// with grid.sync between phases: cvt -> GEMM1 -> quantum -> GEMM2. Removes
// launch gaps, keeps device busy, and makes the kernel visible in rocprof.

#define BB 2048
#define EN 1024

namespace cg = cooperative_groups;

typedef short s16x8 __attribute__((ext_vector_type(8)));
typedef float f32x4 __attribute__((ext_vector_type(4)));

union Frag { s16x8 v; __hip_bfloat16 h[8]; };

__device__ inline s16x8 cvt_frag(f32x4 lo, f32x4 hi) {
    Frag u;
    #pragma unroll
    for (int j = 0; j < 4; ++j) {
        u.h[j]     = __float2bfloat16(lo[j]);
        u.h[4 + j] = __float2bfloat16(hi[j]);
    }
    return u.v;
}

// async 16B/lane global -> LDS (lds base wave-uniform; HW adds lane*16)
__device__ inline void gll16(const __hip_bfloat16* g, __hip_bfloat16* l) {
    __builtin_amdgcn_global_load_lds(
        (const __attribute__((address_space(1))) void*)g,
        (__attribute__((address_space(3))) void*)l,
        16, 0, 0);
}

// One 64x64 output tile of C[m,n] = sum_k A[m,k]*W[n,k]; A,W bf16 K-contig.
// 256 thr (4 waves 2x2), wave tile 32x32, BK=64, double-buffered LDS (32KB),
// frag-ordered LDS tiles (lane l's mfma fragment at tile_base + l*16B).
// EPI 0: bf16 store. EPI 1: f32 store + bias.
template <int EPI>
__device__ void gemm_tile(const __hip_bfloat16* __restrict__ A,
                          const __hip_bfloat16* __restrict__ W,
                          const float* __restrict__ bias,
                          void* __restrict__ Cv,
                          int m0, int n0, int tid,
                          __hip_bfloat16* lds)
{
    const int wave = tid >> 6, lane = tid & 63;
    const int l15 = lane & 15, lq = lane >> 4;
    const int wm = (wave & 1) * 32, wn = (wave >> 1) * 32;

    // wave stages 4 of 16 frag-tiles: t = wave*4+i
    const __hip_bfloat16* gsrc[4];
    int ldst[4];
    #pragma unroll
    for (int i = 0; i < 4; ++i) {
        const int t  = wave * 4 + i;
        const int kt = t & 1;
        int row, lofs;
        const __hip_bfloat16* base;
        if (t < 8) { const int mt = t >> 1;       row = m0 + mt * 16 + l15; base = A; lofs = t * 512; }
        else       { const int nt = (t - 8) >> 1; row = n0 + nt * 16 + l15; base = W; lofs = 4096 + (t - 8) * 512; }
        gsrc[i] = base + (size_t)row * EN + kt * 32 + lq * 8;
        ldst[i] = lofs;
    }

    f32x4 acc[2][2] = {};

    #pragma unroll
    for (int i = 0; i < 4; ++i) gll16(gsrc[i], &lds[ldst[i]]);
    __syncthreads();

    int p = 0;
    for (int k0 = 64; k0 <= EN; k0 += 64) {
        if (k0 < EN) {
            const int q = p ^ 1;
            #pragma unroll
            for (int i = 0; i < 4; ++i) gll16(gsrc[i] + k0, &lds[q * 8192 + ldst[i]]);
        }
        const __hip_bfloat16* Ab = &lds[p * 8192];
        const __hip_bfloat16* Bb = Ab + 4096;
        #pragma unroll
        for (int kt = 0; kt < 2; ++kt) {
            s16x8 a[2], b[2];
            #pragma unroll
            for (int mi = 0; mi < 2; ++mi)
                a[mi] = *(const s16x8*)&Ab[((wm >> 4) + mi) * 1024 + kt * 512 + lane * 8];
            #pragma unroll
            for (int nj = 0; nj < 2; ++nj)
                b[nj] = *(const s16x8*)&Bb[((wn >> 4) + nj) * 1024 + kt * 512 + lane * 8];
            #pragma unroll
            for (int mi = 0; mi < 2; ++mi)
                #pragma unroll
                for (int nj = 0; nj < 2; ++nj)
                    acc[mi][nj] = __builtin_amdgcn_mfma_f32_16x16x32_bf16(
                                      a[mi], b[nj], acc[mi][nj], 0, 0, 0);
        }
        __syncthreads();
        p ^= 1;
    }

    if (EPI == 0) {
        __hip_bfloat16* C = (__hip_bfloat16*)Cv;
        #pragma unroll
        for (int mi = 0; mi < 2; ++mi)
            #pragma unroll
            for (int nj = 0; nj < 2; ++nj) {
                const int col = n0 + wn + nj * 16 + l15;
                #pragma unroll
                for (int r = 0; r < 4; ++r) {
                    const int row = m0 + wm + mi * 16 + lq * 4 + r;
                    C[(size_t)row * EN + col] = __float2bfloat16(acc[mi][nj][r]);
                }
            }
    } else {
        float* C = (float*)Cv;
        #pragma unroll
        for (int nj = 0; nj < 2; ++nj) {
            const int col = n0 + wn + nj * 16 + l15;
            const float bv = bias[col];
            #pragma unroll
            for (int mi = 0; mi < 2; ++mi)
                #pragma unroll
                for (int r = 0; r < 4; ++r) {
                    const int row = m0 + wm + mi * 16 + lq * 4 + r;
                    C[(size_t)row * EN + col] = acc[mi][nj][r] + bv;
                }
        }
    }
}

// Fused pipeline: cvt -> sync -> GEMM1 -> sync -> quantum -> sync -> GEMM2.
// Grid MUST be 512 blocks x 256 threads (cooperative, 2 blocks/CU).
__global__ __launch_bounds__(256, 2) void fused_kernel(
        const float* __restrict__ x,  const float* __restrict__ wv,
        const float* __restrict__ wc, const float* __restrict__ bc,
        const float* __restrict__ rx, float* __restrict__ out,
        __hip_bfloat16* __restrict__ xb, __hip_bfloat16* __restrict__ wvb,
        __hip_bfloat16* __restrict__ wcb, __hip_bfloat16* __restrict__ V)
{
    cg::grid_group grid = cg::this_grid();
    __shared__ __hip_bfloat16 lds[16384];   // 32 KB

    const int tid = threadIdx.x;
    const int bid = blockIdx.x;             // 0..511
    const int tg  = bid * 256 + tid;        // 0..131071

    // ---- phase 0: cvt x (2M elems), wv, wc (1M each) f32 -> bf16 ----
    {
        #pragma unroll
        for (int r = 0; r < 4; ++r) {
            const float* s = (r < 2) ? x : (r == 2 ? wv : wc);
            __hip_bfloat16* d = (r < 2) ? xb : (r == 2 ? wvb : wcb);
            const size_t off = ((size_t)tg + (r == 1 ? 131072u : 0u)) * 8;
            f32x4 lo = *(const f32x4*)(s + off);
            f32x4 hi = *(const f32x4*)(s + off + 4);
            *(s16x8*)(d + off) = cvt_frag(lo, hi);
        }
    }
    grid.sync();

    // ---- phase 1: V = xb @ wvb^T (bf16 out) ----
    const int m0 = (bid >> 4) * 64;   // 32 m-tiles
    const int n0 = (bid & 15) * 64;   // 16 n-tiles
    gemm_tile<0>(xb, wvb, nullptr, V, m0, n0, tid, lds);
    grid.sync();

    // ---- phase 1.5: quantum, in place on V; 2 groups of 8 per thread ----
    {
        float rxl[8];
        #pragma unroll
        for (int j = 0; j < 8; ++j) rxl[j] = rx[j];
        #pragma unroll
        for (int r = 0; r < 2; ++r) {
            const size_t g = (size_t)tg + (size_t)r * 131072u;
            Frag in;
            in.v = *(const s16x8*)(V + g * 8);
            float t[8];
            #pragma unroll
            for (int j = 0; j < 8; ++j)
                t[j] = __cosf(__bfloat162float(in.h[j]) + rxl[j]);
            Frag o;
            float suf = t[1];
            #pragma unroll
            for (int j = 2; j < 8; ++j) suf *= t[j];
            o.h[0] = __float2bfloat16(suf);
            float p = t[0];
            #pragma unroll
            for (int j = 1; j < 8; ++j) { p *= t[j]; o.h[j] = __float2bfloat16(p); }
            *(s16x8*)(V + g * 8) = o.v;
        }
    }
    grid.sync();

    // ---- phase 2: out = V @ wcb^T + bc (f32 out) ----
    gemm_tile<1>(V, wcb, bc, out, m0, n0, tid, lds);
}

extern "C" void kernel_launch(void* const* d_in, const int* in_sizes, int n_in,
                              void* d_out, int out_size, void* d_ws, size_t ws_size,
                              hipStream_t stream)
{
    // inputs: x, wq, wk, wv, wc, bc, rx_params (wq/wk dead: S==1)
    const float* x  = (const float*)d_in[0];
    const float* wv = (const float*)d_in[3];
    const float* wc = (const float*)d_in[4];
    const float* bc = (const float*)d_in[5];
    const float* rx = (const float*)d_in[6];
    float* out = (float*)d_out;

    const size_t XE = (size_t)BB * EN;   // 2M elems
    const size_t WE = (size_t)EN * EN;   // 1M elems

    // ws layout (12 MB): [xb 4MB | wvb 2MB | wcb 2MB | V 4MB]
    __hip_bfloat16* xb  = (__hip_bfloat16*)d_ws;
    __hip_bfloat16* wvb = xb + XE;
    __hip_bfloat16* wcb = wvb + WE;
    __hip_bfloat16* V   = wcb + WE;

    void* args[] = { (void*)&x, (void*)&wv, (void*)&wc, (void*)&bc, (void*)&rx,
                     (void*)&out, (void*)&xb, (void*)&wvb, (void*)&wcb, (void*)&V };
    hipLaunchCooperativeKernel((const void*)fused_kernel,
                               dim3(512), dim3(256), args, 0, stream);
}

// Round 7
// 194.196 us; speedup vs baseline: 1.6454x; 1.6454x over previous
//
#include <hip/hip_runtime.h>
#include <hip/hip_bf16.h>
#include <math.h>

// MultiHeadAttentionQuantum, B=2048 S=1 E=1024 H=128 DK=NW=8
// All inputs/outputs float32.
//
// Algebra: S==1 -> attention out == v = x @ Wv^T (wq,wk dead).
// RX compose additively; CNOTs are XOR basis permutations ->
//   t_j = cos(v_j + rx_j);  qout[0]=t1*...*t7;  qout[w>=1]=t0*...*tw
// out = qout @ Wc^T + bc
//
// R6 post-mortem: grid.sync costs ~50us each (kernel 226us, MfmaUtil 1.5%).
// R7 insight: the pipeline is ROW-BLOCK INDEPENDENT. One block owns 16 rows
// end-to-end: x->V (V lives in LDS) -> quantum (LDS) -> out. No global V,
// no inter-phase sync, no quantum kernel. Cost: each block streams full
// Wv+Wc (4 MB bf16) from L2/L3: 128 blocks * 4 MB = 512 MB ~ 15us floor.

#define EN 1024
#define ROWS 16     // rows per block; grid = 2048/16 = 128 blocks

typedef short s16x8 __attribute__((ext_vector_type(8)));
typedef float f32x4 __attribute__((ext_vector_type(4)));

union Frag { s16x8 v; __hip_bfloat16 h[8]; };

__device__ inline s16x8 cvt_frag(f32x4 lo, f32x4 hi) {
    Frag u;
    #pragma unroll
    for (int j = 0; j < 4; ++j) {
        u.h[j]     = __float2bfloat16(lo[j]);
        u.h[4 + j] = __float2bfloat16(hi[j]);
    }
    return u.v;
}

// Convert wv, wc (1M f32 elems each) -> bf16 in ws.
__global__ __launch_bounds__(256) void cvtw_kernel(
        const float* __restrict__ wv, const float* __restrict__ wc,
        __hip_bfloat16* __restrict__ wvb, __hip_bfloat16* __restrict__ wcb)
{
    const int g = blockIdx.x * 256 + threadIdx.x;      // 0 .. 262143
    const int NG = (EN * EN) / 8;                      // 131072 per matrix
    const float* s = (g < NG) ? wv : wc;
    __hip_bfloat16* d = (g < NG) ? wvb : wcb;
    const size_t off = (size_t)((g < NG) ? g : g - NG) * 8;
    f32x4 lo = *(const f32x4*)(s + off);
    f32x4 hi = *(const f32x4*)(s + off + 4);
    *(s16x8*)(d + off) = cvt_frag(lo, hi);
}

// Fused row-block kernel: 128 blocks x 512 threads (8 waves).
// Block owns rows [m0, m0+16). Wave w owns out-cols [w*128, w*128+128).
//
// LDS: xs = frag-ordered A operand (32 KB): element (m=lane&15, k=kc*32+(lane>>4)*8+j)
//      of the current A matrix lives at xs[(kc*64+lane)*8 + j]. Conflict-free
//      1024B-contiguous wave reads. Reused for qout between GEMM1 and GEMM2.
//      vs = raw V rows [16][1032] bf16 (pad breaks bank alignment).
__global__ __launch_bounds__(512, 2) void fused_kernel(
        const float* __restrict__ x,
        const __hip_bfloat16* __restrict__ wvb,
        const __hip_bfloat16* __restrict__ wcb,
        const float* __restrict__ bc, const float* __restrict__ rx,
        float* __restrict__ out)
{
    __shared__ __hip_bfloat16 xs[32 * 64 * 8];   // 16384 elems, 32 KB
    __shared__ __hip_bfloat16 vs[ROWS * 1032];   // 33 KB

    const int tid  = threadIdx.x;
    const int wave = tid >> 6, lane = tid & 63;
    const int l15 = lane & 15, lq = lane >> 4;
    const int m0 = blockIdx.x * ROWS;

    // ---- stage x rows -> xs (f32->bf16, frag-ordered) ----
    {
        const int r = tid & 15, lq2 = (tid >> 4) & 3, kc0 = tid >> 6;  // kc0 0..7
        #pragma unroll
        for (int p = 0; p < 4; ++p) {
            const int kc = kc0 + 8 * p;
            const int k  = kc * 32 + lq2 * 8;
            const float* px = x + (size_t)(m0 + r) * EN + k;
            f32x4 lo = *(const f32x4*)px;
            f32x4 hi = *(const f32x4*)(px + 4);
            *(s16x8*)&xs[(size_t)(kc * 64 + lq2 * 16 + r) * 8] = cvt_frag(lo, hi);
        }
    }
    __syncthreads();

    // ---- GEMM1: V[0:16, w*128 : w*128+128] = x @ Wv^T ----
    {
        f32x4 acc[8] = {};
        const __hip_bfloat16* wb = wvb + (size_t)(wave * 128 + l15) * EN + lq * 8;
        for (int kc = 0; kc < 32; ++kc) {
            s16x8 a = *(const s16x8*)&xs[(size_t)(kc * 64 + lane) * 8];
            #pragma unroll
            for (int nf = 0; nf < 8; ++nf) {
                s16x8 b = *(const s16x8*)(wb + (size_t)nf * 16 * EN + kc * 32);
                acc[nf] = __builtin_amdgcn_mfma_f32_16x16x32_bf16(a, b, acc[nf], 0, 0, 0);
            }
        }
        // epilogue: acc -> vs raw rows (col = w*128+nf*16+l15, row = lq*4+r)
        #pragma unroll
        for (int nf = 0; nf < 8; ++nf) {
            const int col = wave * 128 + nf * 16 + l15;
            #pragma unroll
            for (int r = 0; r < 4; ++r)
                vs[(lq * 4 + r) * 1032 + col] = __float2bfloat16(acc[nf][r]);
        }
    }
    __syncthreads();

    // ---- quantum: vs rows -> xs (A-frag-ordered qout) ----
    {
        float rxl[8];
        #pragma unroll
        for (int j = 0; j < 8; ++j) rxl[j] = rx[j];
        #pragma unroll
        for (int p = 0; p < 4; ++p) {
            const int idx = p * 512 + tid;      // 0..2047 = 128 groups x 16 rows
            const int g = idx >> 4, r = idx & 15;
            Frag in;
            in.v = *(const s16x8*)&vs[r * 1032 + g * 8];
            float t[8];
            #pragma unroll
            for (int j = 0; j < 8; ++j)
                t[j] = __cosf(__bfloat162float(in.h[j]) + rxl[j]);
            Frag o;
            float suf = t[1];
            #pragma unroll
            for (int j = 2; j < 8; ++j) suf *= t[j];
            o.h[0] = __float2bfloat16(suf);
            float pr = t[0];
            #pragma unroll
            for (int j = 1; j < 8; ++j) { pr *= t[j]; o.h[j] = __float2bfloat16(pr); }
            const int kc = g >> 2, lq2 = g & 3;
            *(s16x8*)&xs[(size_t)(kc * 64 + lq2 * 16 + r) * 8] = o.v;
        }
    }
    __syncthreads();

    // ---- GEMM2: out[0:16, w*128 : +128] = qout @ Wc^T + bc ----
    {
        f32x4 acc[8] = {};
        const __hip_bfloat16* wb = wcb + (size_t)(wave * 128 + l15) * EN + lq * 8;
        for (int kc = 0; kc < 32; ++kc) {
            s16x8 a = *(const s16x8*)&xs[(size_t)(kc * 64 + lane) * 8];
            #pragma unroll
            for (int nf = 0; nf < 8; ++nf) {
                s16x8 b = *(const s16x8*)(wb + (size_t)nf * 16 * EN + kc * 32);
                acc[nf] = __builtin_amdgcn_mfma_f32_16x16x32_bf16(a, b, acc[nf], 0, 0, 0);
            }
        }
        #pragma unroll
        for (int nf = 0; nf < 8; ++nf) {
            const int col = wave * 128 + nf * 16 + l15;
            const float bv = bc[col];
            #pragma unroll
            for (int r = 0; r < 4; ++r)
                out[(size_t)(m0 + lq * 4 + r) * EN + col] = acc[nf][r] + bv;
        }
    }
}

extern "C" void kernel_launch(void* const* d_in, const int* in_sizes, int n_in,
                              void* d_out, int out_size, void* d_ws, size_t ws_size,
                              hipStream_t stream)
{
    // inputs: x, wq, wk, wv, wc, bc, rx_params (wq/wk dead: S==1)
    const float* x  = (const float*)d_in[0];
    const float* wv = (const float*)d_in[3];
    const float* wc = (const float*)d_in[4];
    const float* bc = (const float*)d_in[5];
    const float* rx = (const float*)d_in[6];
    float* out = (float*)d_out;

    const size_t WE = (size_t)EN * EN;
    __hip_bfloat16* wvb = (__hip_bfloat16*)d_ws;     // 2 MB
    __hip_bfloat16* wcb = wvb + WE;                  // 2 MB

    cvtw_kernel<<<(int)(2 * (WE / 8) / 256), 256, 0, stream>>>(wv, wc, wvb, wcb);
    fused_kernel<<<2048 / ROWS, 512, 0, stream>>>(x, wvb, wcb, bc, rx, out);
}

// Round 8
// 112.270 us; speedup vs baseline: 2.8461x; 1.7297x over previous
//
#include <hip/hip_runtime.h>
#include <hip/hip_bf16.h>
#include <math.h>

// MultiHeadAttentionQuantum, B=2048 S=1 E=1024 H=128 DK=NW=8
// All inputs/outputs float32.
//
// Algebra: S==1 -> attention out == v = x @ Wv^T (wq,wk dead).
// RX compose additively; CNOTs are XOR basis permutations ->
//   t_j = cos(v_j + rx_j);  qout[0]=t1*...*t7;  qout[w>=1]=t0*...*tw
// out = qout @ Wc^T + bc
//
// R7 post-mortem: TM=16/TN=1024 tiling = 256 MB weight re-stream/GEMM +
// half-idle CUs -> 121us. Tile-traffic law: A*(N/TN)+B*(M/TM); 64x64 is near
// optimal at this shape AND gives 512 blocks. R8 = R5's proven 64x64
// async-staged GEMM, but: 512 threads/block (16 waves/CU, 2x the TLP of R5),
// quantum fused into GEMM1 epilogue via in-LDS transpose (3 kernels, one
// less V pass).

#define BB 2048
#define EN 1024

typedef short s16x8 __attribute__((ext_vector_type(8)));
typedef float f32x4 __attribute__((ext_vector_type(4)));

union Frag { s16x8 v; __hip_bfloat16 h[8]; };

__device__ inline s16x8 cvt_frag(f32x4 lo, f32x4 hi) {
    Frag u;
    #pragma unroll
    for (int j = 0; j < 4; ++j) {
        u.h[j]     = __float2bfloat16(lo[j]);
        u.h[4 + j] = __float2bfloat16(hi[j]);
    }
    return u.v;
}

// async 16B/lane global -> LDS (lds base wave-uniform; HW adds lane*16)
__device__ inline void gll16(const __hip_bfloat16* g, __hip_bfloat16* l) {
    __builtin_amdgcn_global_load_lds(
        (const __attribute__((address_space(1))) void*)g,
        (__attribute__((address_space(3))) void*)l,
        16, 0, 0);
}

// Convert x (262144 groups), wv, wc (131072 groups each) -> bf16.
__global__ __launch_bounds__(256) void cvt3_kernel(
        const float* __restrict__ x, const float* __restrict__ wv,
        const float* __restrict__ wc,
        __hip_bfloat16* __restrict__ xb, __hip_bfloat16* __restrict__ wvb,
        __hip_bfloat16* __restrict__ wcb)
{
    const int g = blockIdx.x * 256 + threadIdx.x;   // 0 .. 524287
    const int NX = (BB * EN) / 8;                   // 262144
    const int NG = (EN * EN) / 8;                   // 131072
    const float* s; __hip_bfloat16* d; size_t off;
    if (g < NX)           { s = x;  d = xb;  off = (size_t)g * 8; }
    else if (g < NX + NG) { s = wv; d = wvb; off = (size_t)(g - NX) * 8; }
    else                  { s = wc; d = wcb; off = (size_t)(g - NX - NG) * 8; }
    f32x4 lo = *(const f32x4*)(s + off);
    f32x4 hi = *(const f32x4*)(s + off + 4);
    *(s16x8*)(d + off) = cvt_frag(lo, hi);
}

// GEMM: C[m,n] = sum_k A[m,k]*W[n,k]; A 2048xEN bf16, W ENxEN bf16.
// Tile 64x64, 512 thr = 8 waves (4m x 2n), wave tile 16x32, BK=64,
// double-buffered frag-ordered LDS (32 KB): frag-tile = 512 elems (16 rows x
// 32 k), lane l's mfma fragment at tile_base + l*8 elems. A tile (mt,kt) at
// (mt*2+kt)*512; B tile (nt,kt) at 4096+(nt*2+kt)*512.
// EPI 0: quantum epilogue (in-LDS 64x64 transpose) -> bf16 V.
// EPI 1: +bias -> f32 out.
template <int EPI>
__global__ __launch_bounds__(512, 4) void gemm_kernel(
        const __hip_bfloat16* __restrict__ A,
        const __hip_bfloat16* __restrict__ W,
        const float* __restrict__ bias, const float* __restrict__ rx,
        void* __restrict__ Cv)
{
    __shared__ __align__(16) unsigned char smem[32768];
    __hip_bfloat16* lds = (__hip_bfloat16*)smem;

    const int tid  = threadIdx.x;
    const int wave = tid >> 6, lane = tid & 63;
    const int l15 = lane & 15, lq = lane >> 4;
    const int m0 = blockIdx.x * 64, n0 = blockIdx.y * 64;
    const int wmt = wave >> 1;          // 0..3  (16-row wave tile)
    const int wnt = wave & 1;           // 0..1  (32-col wave tile)

    // staging: wave stages 2 of 16 frag-tiles: t = wave*2 + i
    const __hip_bfloat16* gsrc[2];
    int ldst[2];
    #pragma unroll
    for (int i = 0; i < 2; ++i) {
        const int t = wave * 2 + i;
        int row, lofs;
        const __hip_bfloat16* base;
        if (t < 8) { const int mt = t >> 1; row = m0 + mt * 16 + l15; base = A; lofs = t * 512; }
        else       { const int u = t - 8;   row = n0 + (u >> 1) * 16 + l15; base = W; lofs = 4096 + u * 512; }
        gsrc[i] = base + (size_t)row * EN + (t & 1) * 32 + lq * 8;
        ldst[i] = lofs;
    }

    f32x4 acc[2] = {};

    #pragma unroll
    for (int i = 0; i < 2; ++i) gll16(gsrc[i], &lds[ldst[i]]);
    __syncthreads();

    int p = 0;
    for (int k0 = 64; k0 <= EN; k0 += 64) {
        if (k0 < EN) {
            const int q = p ^ 1;
            #pragma unroll
            for (int i = 0; i < 2; ++i) gll16(gsrc[i] + k0, &lds[q * 8192 + ldst[i]]);
        }
        const __hip_bfloat16* Ab = &lds[p * 8192];
        const __hip_bfloat16* Bb = Ab + 4096;
        #pragma unroll
        for (int kt = 0; kt < 2; ++kt) {
            s16x8 a = *(const s16x8*)&Ab[(wmt * 2 + kt) * 512 + lane * 8];
            #pragma unroll
            for (int j = 0; j < 2; ++j) {
                s16x8 b = *(const s16x8*)&Bb[((wnt * 2 + j) * 2 + kt) * 512 + lane * 8];
                acc[j] = __builtin_amdgcn_mfma_f32_16x16x32_bf16(a, b, acc[j], 0, 0, 0);
            }
        }
        __syncthreads();
        p ^= 1;
    }

    if (EPI == 0) {
        // quantum epilogue: acc -> LDS f32 64x68 -> cos/products -> bf16 V
        float* sb = (float*)smem;                       // 17408 B, lds is free
        #pragma unroll
        for (int j = 0; j < 2; ++j) {
            const int col = wnt * 32 + j * 16 + l15;
            #pragma unroll
            for (int r = 0; r < 4; ++r)
                sb[(wmt * 16 + lq * 4 + r) * 68 + col] = acc[j][r];
        }
        __syncthreads();
        const int row = tid >> 3, g = tid & 7;          // 64 rows x 8 groups
        const float* pv = &sb[row * 68 + g * 8];
        float t[8];
        #pragma unroll
        for (int j = 0; j < 8; ++j) t[j] = __cosf(pv[j] + rx[j]);
        Frag o;
        float suf = t[1];
        #pragma unroll
        for (int j = 2; j < 8; ++j) suf *= t[j];
        o.h[0] = __float2bfloat16(suf);
        float pr = t[0];
        #pragma unroll
        for (int j = 1; j < 8; ++j) { pr *= t[j]; o.h[j] = __float2bfloat16(pr); }
        __hip_bfloat16* V = (__hip_bfloat16*)Cv;
        *(s16x8*)(V + (size_t)(m0 + row) * EN + n0 + g * 8) = o.v;
    } else {
        float* C = (float*)Cv;
        #pragma unroll
        for (int j = 0; j < 2; ++j) {
            const int col = n0 + wnt * 32 + j * 16 + l15;
            const float bv = bias[col];
            #pragma unroll
            for (int r = 0; r < 4; ++r) {
                const int row = m0 + wmt * 16 + lq * 4 + r;
                C[(size_t)row * EN + col] = acc[j][r] + bv;
            }
        }
    }
}

extern "C" void kernel_launch(void* const* d_in, const int* in_sizes, int n_in,
                              void* d_out, int out_size, void* d_ws, size_t ws_size,
                              hipStream_t stream)
{
    // inputs: x, wq, wk, wv, wc, bc, rx_params (wq/wk dead: S==1)
    const float* x  = (const float*)d_in[0];
    const float* wv = (const float*)d_in[3];
    const float* wc = (const float*)d_in[4];
    const float* bc = (const float*)d_in[5];
    const float* rx = (const float*)d_in[6];
    float* out = (float*)d_out;

    const size_t XE = (size_t)BB * EN;   // 2M elems
    const size_t WE = (size_t)EN * EN;   // 1M elems

    // ws (12 MB): [xb 4MB | wvb 2MB | wcb 2MB | V 4MB]
    __hip_bfloat16* xb  = (__hip_bfloat16*)d_ws;
    __hip_bfloat16* wvb = xb + XE;
    __hip_bfloat16* wcb = wvb + WE;
    __hip_bfloat16* V   = wcb + WE;

    dim3 grid(BB / 64, EN / 64);         // 32 x 16 = 512 blocks
    cvt3_kernel<<<(int)((XE / 8 + 2 * (WE / 8)) / 256), 256, 0, stream>>>(
        x, wv, wc, xb, wvb, wcb);
    gemm_kernel<0><<<grid, 512, 0, stream>>>(xb, wvb, nullptr, rx, V);
    gemm_kernel<1><<<grid, 512, 0, stream>>>(V, wcb, bc, nullptr, out);
}